// Round 1
// baseline (1045.931 us; speedup 1.0000x reference)
//
#include <hip/hip_runtime.h>
#include <hip/hip_bf16.h>
#include <math.h>

// ---------------- problem constants ----------------
#define T_TOKENS 8192          // B*S = 4*2048
#define D_MODEL  1024
#define N_EXP    8
#define I_RAW    2752
#define I_PAD    2816          // 22 * 128, zero-padded
#define MAXROWS  17408         // 16384 + 8*128 (per-expert 128-alignment padding)

typedef __attribute__((ext_vector_type(8))) short bf16x8;
typedef __attribute__((ext_vector_type(4))) float f32x4;
typedef unsigned short ushort_t;

// ctrl layout (ints): [0..7] counts, [8..15] cursor, [16..24] seg offsets
#define CTRL_COUNT 0
#define CTRL_CUR   8
#define CTRL_SEG   16

__device__ __forceinline__ void gll16(const void* g, void* l) {
  __builtin_amdgcn_global_load_lds(
      (const __attribute__((address_space(1))) void*)g,
      (__attribute__((address_space(3))) void*)l, 16, 0, 0);
}

// ---------------- router: one wave per token ----------------
__global__ void __launch_bounds__(64) router_kernel(
    const float* __restrict__ x, const float* __restrict__ rw,
    int* __restrict__ topidx, float* __restrict__ topw, int* __restrict__ ctrl) {
  const int t = blockIdx.x;
  const int lane = threadIdx.x;
  const float* xr = x + (size_t)t * D_MODEL;
  float acc[N_EXP];
#pragma unroll
  for (int e = 0; e < N_EXP; ++e) acc[e] = 0.f;
  for (int d = lane; d < D_MODEL; d += 64) {
    const float xv = xr[d];
    const float* r = rw + (size_t)d * N_EXP;
#pragma unroll
    for (int e = 0; e < N_EXP; ++e) acc[e] = fmaf(xv, r[e], acc[e]);
  }
#pragma unroll
  for (int e = 0; e < N_EXP; ++e) {
    for (int off = 32; off > 0; off >>= 1) acc[e] += __shfl_xor(acc[e], off, 64);
  }
  if (lane == 0) {
    float m = acc[0];
#pragma unroll
    for (int e = 1; e < N_EXP; ++e) m = fmaxf(m, acc[e]);
    float p[N_EXP], s = 0.f;
#pragma unroll
    for (int e = 0; e < N_EXP; ++e) { p[e] = expf(acc[e] - m); s += p[e]; }
    // top-2 (first index wins ties, matching lax.top_k)
    int i0 = 0; float v0 = p[0];
#pragma unroll
    for (int e = 1; e < N_EXP; ++e) if (p[e] > v0) { v0 = p[e]; i0 = e; }
    int i1 = -1; float v1 = -1.f;
#pragma unroll
    for (int e = 0; e < N_EXP; ++e) if (e != i0 && p[e] > v1) { v1 = p[e]; i1 = e; }
    v0 /= s; v1 /= s;
    const float r = v0 + v1 + 1e-6f;
    v0 /= r; v1 /= r;
    topidx[t * 2] = i0; topidx[t * 2 + 1] = i1;
    topw[t * 2] = v0;  topw[t * 2 + 1] = v1;
    atomicAdd(&ctrl[CTRL_COUNT + i0], 1);
    atomicAdd(&ctrl[CTRL_COUNT + i1], 1);
  }
}

// ---------------- x -> bf16 ----------------
__global__ void cvt_x_kernel(const float* __restrict__ x,
                             __hip_bfloat16* __restrict__ xb, int n4) {
  const int i = blockIdx.x * blockDim.x + threadIdx.x;
  if (i < n4) {
    const float4 v = ((const float4*)x)[i];
    __hip_bfloat16 b0 = __float2bfloat16(v.x), b1 = __float2bfloat16(v.y);
    __hip_bfloat16 b2 = __float2bfloat16(v.z), b3 = __float2bfloat16(v.w);
    ushort4 o;
    o.x = reinterpret_cast<ushort_t&>(b0); o.y = reinterpret_cast<ushort_t&>(b1);
    o.z = reinterpret_cast<ushort_t&>(b2); o.w = reinterpret_cast<ushort_t&>(b3);
    ((ushort4*)xb)[i] = o;
  }
}

// ---------------- transpose + convert: out[r][c] = (c<Ri && r<Ci) ? in[c][r] : 0 ----------------
__global__ void __launch_bounds__(256) transpose_cvt_kernel(
    const float* __restrict__ in, __hip_bfloat16* __restrict__ out,
    int Ri, int Ci, int Ro, int Co, long in_es, long out_es) {
  __shared__ float tile[32][33];
  const float* inp = in + (size_t)blockIdx.z * in_es;
  __hip_bfloat16* outp = out + (size_t)blockIdx.z * out_es;
  const int r0 = blockIdx.y * 32, c0 = blockIdx.x * 32;
  const int tx = threadIdx.x, ty = threadIdx.y;   // block (32,8)
#pragma unroll
  for (int i = 0; i < 4; ++i) {
    const int ir = ty + i * 8;
    const int grow = c0 + ir, gcol = r0 + tx;
    float v = (grow < Ri && gcol < Ci) ? inp[(size_t)grow * Ci + gcol] : 0.f;
    tile[ir][tx] = v;
  }
  __syncthreads();
#pragma unroll
  for (int i = 0; i < 4; ++i) {
    const int orow = r0 + ty + i * 8, ocol = c0 + tx;
    outp[(size_t)orow * Co + ocol] = __float2bfloat16(tile[tx][ty + i * 8]);
  }
}

// ---------------- pad fill ----------------
__global__ void padfill_kernel(int* __restrict__ rowmap, float* __restrict__ roww) {
  const int i = blockIdx.x * blockDim.x + threadIdx.x;
  if (i < MAXROWS) { rowmap[i] = 0; roww[i] = 0.f; }
}

// ---------------- scan: 128-aligned segment offsets ----------------
__global__ void scan_kernel(int* __restrict__ ctrl) {
  if (threadIdx.x == 0 && blockIdx.x == 0) {
    int s = 0;
    ctrl[CTRL_SEG] = 0;
    for (int e = 0; e < N_EXP; ++e) {
      const int c = ctrl[CTRL_COUNT + e];
      s += (c + 127) & ~127;
      ctrl[CTRL_SEG + 1 + e] = s;
    }
  }
}

// ---------------- scatter ----------------
__global__ void scatter_kernel(const int* __restrict__ topidx, const float* __restrict__ topw,
                               int* __restrict__ ctrl, int* __restrict__ rowmap,
                               float* __restrict__ roww) {
  const int t = blockIdx.x * blockDim.x + threadIdx.x;
  if (t >= T_TOKENS) return;
#pragma unroll
  for (int k = 0; k < 2; ++k) {
    const int e = topidx[t * 2 + k];
    const int pos = ctrl[CTRL_SEG + e] + atomicAdd(&ctrl[CTRL_CUR + e], 1);
    rowmap[pos] = t * 2 + k;
    roww[pos] = topw[t * 2 + k];
  }
}

// ---------------- GEMM1: H = silu(Xg @ Wg) * (Xg @ Wu), bf16 out ----------------
// A: gathered xb rows [128 x 64/k-step], B: wgt/wut [E][I_PAD][D] (n-major, k contiguous)
__global__ void __launch_bounds__(256) gemm1_kernel(
    const __hip_bfloat16* __restrict__ xb,
    const __hip_bfloat16* __restrict__ wgt,
    const __hip_bfloat16* __restrict__ wut,
    __hip_bfloat16* __restrict__ H,
    const int* __restrict__ rowmap, const int* __restrict__ ctrl) {
  const int e = blockIdx.z;
  const int s0 = ctrl[CTRL_SEG + e], s1 = ctrl[CTRL_SEG + e + 1];
  const int mbase = blockIdx.y * 128;
  if (mbase >= s1 - s0) return;
  const int nbase = blockIdx.x * 128;
  const int tid = threadIdx.x, lane = tid & 63, wid = tid >> 6;

  __shared__ __align__(16) __hip_bfloat16 sA[128 * 64];
  __shared__ __align__(16) __hip_bfloat16 sBg[128 * 64];
  __shared__ __align__(16) __hip_bfloat16 sBu[128 * 64];

  // staging assignment: chunk c = i*256 + tid; row = c>>3; pcol = c&7; lcol = pcol ^ (row&7)
  const __hip_bfloat16* ga[4]; const __hip_bfloat16* gg[4]; const __hip_bfloat16* gu[4];
#pragma unroll
  for (int i = 0; i < 4; ++i) {
    const int row = i * 32 + (tid >> 3);
    const int lcol = (tid & 7) ^ (row & 7);
    const int tok = rowmap[s0 + mbase + row] >> 1;
    ga[i] = xb + (size_t)tok * D_MODEL + lcol * 8;
    gg[i] = wgt + ((size_t)e * I_PAD + nbase + row) * D_MODEL + lcol * 8;
    gu[i] = wut + ((size_t)e * I_PAD + nbase + row) * D_MODEL + lcol * 8;
  }

  f32x4 accg[4][4], accu[4][4];
  const f32x4 z4 = {0.f, 0.f, 0.f, 0.f};
#pragma unroll
  for (int a = 0; a < 4; ++a)
#pragma unroll
    for (int b = 0; b < 4; ++b) { accg[a][b] = z4; accu[a][b] = z4; }

  const int wr = (wid >> 1) * 64, wc = (wid & 1) * 64;

  for (int kt = 0; kt < D_MODEL / 64; ++kt) {
#pragma unroll
    for (int i = 0; i < 4; ++i) {
      const unsigned lo = i * 2048 + wid * 512;   // element offset of wave's 1KB chunk
      gll16(ga[i] + kt * 64, &sA[lo]);
      gll16(gg[i] + kt * 64, &sBg[lo]);
      gll16(gu[i] + kt * 64, &sBu[lo]);
    }
    __syncthreads();
#pragma unroll
    for (int ks = 0; ks < 2; ++ks) {
      bf16x8 af[4], bg[4], bu[4];
#pragma unroll
      for (int mi = 0; mi < 4; ++mi) {
        const int row = wr + mi * 16 + (lane & 15);
        const int p = (ks * 4 + (lane >> 4)) ^ (row & 7);
        af[mi] = *(const bf16x8*)&sA[row * 64 + p * 8];
      }
#pragma unroll
      for (int ni = 0; ni < 4; ++ni) {
        const int row = wc + ni * 16 + (lane & 15);
        const int p = (ks * 4 + (lane >> 4)) ^ (row & 7);
        bg[ni] = *(const bf16x8*)&sBg[row * 64 + p * 8];
        bu[ni] = *(const bf16x8*)&sBu[row * 64 + p * 8];
      }
#pragma unroll
      for (int mi = 0; mi < 4; ++mi)
#pragma unroll
        for (int ni = 0; ni < 4; ++ni) {
          accg[mi][ni] = __builtin_amdgcn_mfma_f32_16x16x32_bf16(af[mi], bg[ni], accg[mi][ni], 0, 0, 0);
          accu[mi][ni] = __builtin_amdgcn_mfma_f32_16x16x32_bf16(af[mi], bu[ni], accu[mi][ni], 0, 0, 0);
        }
    }
    __syncthreads();
  }

  const size_t hrow0 = (size_t)(s0 + mbase);
#pragma unroll
  for (int mi = 0; mi < 4; ++mi) {
    const int row = wr + mi * 16 + ((lane >> 4) * 4);
#pragma unroll
    for (int ni = 0; ni < 4; ++ni) {
      const int col = nbase + wc + ni * 16 + (lane & 15);
      const f32x4 g = accg[mi][ni], u = accu[mi][ni];
#pragma unroll
      for (int j = 0; j < 4; ++j) {
        const float gv = g[j];
        const float h = gv / (1.f + __expf(-gv)) * u[j];
        H[(hrow0 + row + j) * I_PAD + col] = __float2bfloat16(h);
      }
    }
  }
}

// ---------------- GEMM2: out[tok] += w * (H @ Wd) ----------------
__global__ void __launch_bounds__(256) gemm2_kernel(
    const __hip_bfloat16* __restrict__ H,
    const __hip_bfloat16* __restrict__ wdt,   // [E][D][I_PAD] (n-major, k contiguous)
    float* __restrict__ out,
    const int* __restrict__ rowmap, const float* __restrict__ roww,
    const int* __restrict__ ctrl) {
  const int e = blockIdx.z;
  const int s0 = ctrl[CTRL_SEG + e], s1 = ctrl[CTRL_SEG + e + 1];
  const int mbase = blockIdx.y * 128;
  if (mbase >= s1 - s0) return;
  const int nbase = blockIdx.x * 128;
  const int tid = threadIdx.x, lane = tid & 63, wid = tid >> 6;

  __shared__ __align__(16) __hip_bfloat16 sA[128 * 64];
  __shared__ __align__(16) __hip_bfloat16 sB[128 * 64];
  __shared__ int sTok[128];
  __shared__ float sW[128];

  if (tid < 128) {
    const int rm = rowmap[s0 + mbase + tid];
    sTok[tid] = rm >> 1;
    sW[tid] = roww[s0 + mbase + tid];
  }

  const __hip_bfloat16* ga[4]; const __hip_bfloat16* gb[4];
#pragma unroll
  for (int i = 0; i < 4; ++i) {
    const int row = i * 32 + (tid >> 3);
    const int lcol = (tid & 7) ^ (row & 7);
    ga[i] = H + (size_t)(s0 + mbase + row) * I_PAD + lcol * 8;
    gb[i] = wdt + ((size_t)e * D_MODEL + nbase + row) * I_PAD + lcol * 8;
  }

  f32x4 acc[4][4];
  const f32x4 z4 = {0.f, 0.f, 0.f, 0.f};
#pragma unroll
  for (int a = 0; a < 4; ++a)
#pragma unroll
    for (int b = 0; b < 4; ++b) acc[a][b] = z4;

  const int wr = (wid >> 1) * 64, wc = (wid & 1) * 64;

  for (int kt = 0; kt < I_PAD / 64; ++kt) {
#pragma unroll
    for (int i = 0; i < 4; ++i) {
      const unsigned lo = i * 2048 + wid * 512;
      gll16(ga[i] + kt * 64, &sA[lo]);
      gll16(gb[i] + kt * 64, &sB[lo]);
    }
    __syncthreads();
#pragma unroll
    for (int ks = 0; ks < 2; ++ks) {
      bf16x8 af[4], bf[4];
#pragma unroll
      for (int mi = 0; mi < 4; ++mi) {
        const int row = wr + mi * 16 + (lane & 15);
        const int p = (ks * 4 + (lane >> 4)) ^ (row & 7);
        af[mi] = *(const bf16x8*)&sA[row * 64 + p * 8];
      }
#pragma unroll
      for (int ni = 0; ni < 4; ++ni) {
        const int row = wc + ni * 16 + (lane & 15);
        const int p = (ks * 4 + (lane >> 4)) ^ (row & 7);
        bf[ni] = *(const bf16x8*)&sB[row * 64 + p * 8];
      }
#pragma unroll
      for (int mi = 0; mi < 4; ++mi)
#pragma unroll
        for (int ni = 0; ni < 4; ++ni)
          acc[mi][ni] = __builtin_amdgcn_mfma_f32_16x16x32_bf16(af[mi], bf[ni], acc[mi][ni], 0, 0, 0);
    }
    __syncthreads();
  }

#pragma unroll
  for (int mi = 0; mi < 4; ++mi) {
    const int rowb = wr + mi * 16 + ((lane >> 4) * 4);
#pragma unroll
    for (int ni = 0; ni < 4; ++ni) {
      const int col = nbase + wc + ni * 16 + (lane & 15);
#pragma unroll
      for (int j = 0; j < 4; ++j) {
        const int lr = rowb + j;
        const float v = acc[mi][ni][j] * sW[lr];
        atomicAdd(&out[(size_t)sTok[lr] * D_MODEL + col], v);
      }
    }
  }
}

// ---------------- launch ----------------
extern "C" void kernel_launch(void* const* d_in, const int* in_sizes, int n_in,
                              void* d_out, int out_size, void* d_ws, size_t ws_size,
                              hipStream_t stream) {
  (void)in_sizes; (void)n_in; (void)ws_size;
  const float* x  = (const float*)d_in[0];
  const float* rw = (const float*)d_in[1];
  const float* wg = (const float*)d_in[2];
  const float* wu = (const float*)d_in[3];
  const float* wd = (const float*)d_in[4];
  float* out = (float*)d_out;

  char* ws = (char*)d_ws;
  size_t off = 0;
  auto alloc = [&](size_t bytes) -> char* {
    char* p = ws + off;
    off += (bytes + 255) & ~(size_t)255;
    return p;
  };

  int*   ctrl   = (int*)alloc(256);
  int*   topidx = (int*)alloc((size_t)T_TOKENS * 2 * 4);
  float* topw   = (float*)alloc((size_t)T_TOKENS * 2 * 4);
  int*   rowmap = (int*)alloc((size_t)MAXROWS * 4);
  float* roww   = (float*)alloc((size_t)MAXROWS * 4);
  __hip_bfloat16* xb  = (__hip_bfloat16*)alloc((size_t)T_TOKENS * D_MODEL * 2);
  __hip_bfloat16* wgt = (__hip_bfloat16*)alloc((size_t)N_EXP * I_PAD * D_MODEL * 2);
  __hip_bfloat16* wut = (__hip_bfloat16*)alloc((size_t)N_EXP * I_PAD * D_MODEL * 2);
  __hip_bfloat16* wdt = (__hip_bfloat16*)alloc((size_t)N_EXP * D_MODEL * I_PAD * 2);
  __hip_bfloat16* Hbuf = (__hip_bfloat16*)alloc((size_t)MAXROWS * I_PAD * 2);

  hipMemsetAsync(ctrl, 0, 256, stream);
  hipMemsetAsync(out, 0, (size_t)out_size * 4, stream);

  cvt_x_kernel<<<(T_TOKENS * D_MODEL / 4 + 255) / 256, 256, 0, stream>>>(
      x, xb, T_TOKENS * D_MODEL / 4);

  dim3 tb(32, 8);
  // wg [E][1024][2752] -> wgt [E][2816][1024]
  transpose_cvt_kernel<<<dim3(D_MODEL / 32, I_PAD / 32, N_EXP), tb, 0, stream>>>(
      wg, wgt, D_MODEL, I_RAW, I_PAD, D_MODEL, (long)D_MODEL * I_RAW, (long)I_PAD * D_MODEL);
  transpose_cvt_kernel<<<dim3(D_MODEL / 32, I_PAD / 32, N_EXP), tb, 0, stream>>>(
      wu, wut, D_MODEL, I_RAW, I_PAD, D_MODEL, (long)D_MODEL * I_RAW, (long)I_PAD * D_MODEL);
  // wd [E][2752][1024] -> wdt [E][1024][2816]
  transpose_cvt_kernel<<<dim3(I_PAD / 32, D_MODEL / 32, N_EXP), tb, 0, stream>>>(
      wd, wdt, I_RAW, D_MODEL, D_MODEL, I_PAD, (long)I_RAW * D_MODEL, (long)D_MODEL * I_PAD);

  router_kernel<<<T_TOKENS, 64, 0, stream>>>(x, rw, topidx, topw, ctrl);
  padfill_kernel<<<(MAXROWS + 255) / 256, 256, 0, stream>>>(rowmap, roww);
  scan_kernel<<<1, 64, 0, stream>>>(ctrl);
  scatter_kernel<<<(T_TOKENS + 255) / 256, 256, 0, stream>>>(topidx, topw, ctrl, rowmap, roww);

  gemm1_kernel<<<dim3(I_PAD / 128, 64, N_EXP), 256, 0, stream>>>(
      xb, wgt, wut, Hbuf, rowmap, ctrl);
  gemm2_kernel<<<dim3(D_MODEL / 128, 64, N_EXP), 256, 0, stream>>>(
      Hbuf, wdt, out, rowmap, roww, ctrl);
}